// Round 1
// baseline (51.176 us; speedup 1.0000x reference)
//
#include <hip/hip_runtime.h>
#include <math.h>

#define N_PER_B 262144
#define BATCH 8
#define NFEAT 14

// Kernel 1: per-batch accumulation of the 6 unique entries of T = sum_n r r^T.
// blockIdx.y = batch index; grid-stride over N within the batch.
__global__ __launch_bounds__(256) void accum_kernel(const float* __restrict__ g,
                                                    double* __restrict__ acc) {
    const int b = blockIdx.y;
    const float* __restrict__ gb = g + (size_t)b * N_PER_B * NFEAT;

    double s0 = 0.0, s1 = 0.0, s2 = 0.0, s3 = 0.0, s4 = 0.0, s5 = 0.0;

    const int stride = blockDim.x * gridDim.x;
    for (int i = blockIdx.x * blockDim.x + threadIdx.x; i < N_PER_B; i += stride) {
        const float* __restrict__ p = gb + (size_t)i * NFEAT;
        float w = p[7];
        float x = p[8];
        float y = p[9];
        float z = p[10];

        // _sanitize_finite(q, clamp_abs=1000): inputs are finite normals, but
        // apply the clamp to match semantics exactly.
        w = fminf(fmaxf(w, -1000.0f), 1000.0f);
        x = fminf(fmaxf(x, -1000.0f), 1000.0f);
        y = fminf(fmaxf(y, -1000.0f), 1000.0f);
        z = fminf(fmaxf(z, -1000.0f), 1000.0f);

        float nrm = sqrtf(w * w + x * x + y * y + z * z);
        nrm = fmaxf(nrm, 1e-8f);
        float inv = 1.0f / nrm;
        w *= inv; x *= inv; y *= inv; z *= inv;

        // r = R @ e_z = third column of the rotation matrix
        float r0 = 2.0f * (x * z + w * y);
        float r1 = 2.0f * (y * z - w * x);
        float r2 = 1.0f - 2.0f * (x * x + y * y);

        s0 += (double)r0 * (double)r0;
        s1 += (double)r1 * (double)r1;
        s2 += (double)r2 * (double)r2;
        s3 += (double)r0 * (double)r1;
        s4 += (double)r0 * (double)r2;
        s5 += (double)r1 * (double)r2;
    }

    // wave (64-lane) shuffle reduction
    #pragma unroll
    for (int off = 32; off > 0; off >>= 1) {
        s0 += __shfl_down(s0, off);
        s1 += __shfl_down(s1, off);
        s2 += __shfl_down(s2, off);
        s3 += __shfl_down(s3, off);
        s4 += __shfl_down(s4, off);
        s5 += __shfl_down(s5, off);
    }

    __shared__ double lds[4][6];
    const int wave = threadIdx.x >> 6;
    const int lane = threadIdx.x & 63;
    if (lane == 0) {
        lds[wave][0] = s0; lds[wave][1] = s1; lds[wave][2] = s2;
        lds[wave][3] = s3; lds[wave][4] = s4; lds[wave][5] = s5;
    }
    __syncthreads();

    if (threadIdx.x == 0) {
        #pragma unroll
        for (int k = 0; k < 6; ++k) {
            double t = lds[0][k] + lds[1][k] + lds[2][k] + lds[3][k];
            atomicAdd(&acc[b * 6 + k], t);
        }
    }
}

// Kernel 2: per-batch 3x3 symmetric eigenvalues (closed form, fp64) -> loss.
__global__ void finalize_kernel(const double* __restrict__ acc,
                                float* __restrict__ out) {
    __shared__ double losses[BATCH];
    const int b = threadIdx.x;
    if (b < BATCH) {
        const double invN = 1.0 / (double)N_PER_B;
        double a00 = acc[b * 6 + 0] * invN;
        double a11 = acc[b * 6 + 1] * invN;
        double a22 = acc[b * 6 + 2] * invN;
        double a01 = acc[b * 6 + 3] * invN;
        double a02 = acc[b * 6 + 4] * invN;
        double a12 = acc[b * 6 + 5] * invN;

        // _sanitize_finite(T, clamp_abs=1e6) — no-op for this data, but match.
        a00 = fmin(fmax(a00, -1e6), 1e6);
        a11 = fmin(fmax(a11, -1e6), 1e6);
        a22 = fmin(fmax(a22, -1e6), 1e6);
        a01 = fmin(fmax(a01, -1e6), 1e6);
        a02 = fmin(fmax(a02, -1e6), 1e6);
        a12 = fmin(fmax(a12, -1e6), 1e6);

        // Smith's closed-form eigenvalues of a symmetric 3x3
        double q = (a00 + a11 + a22) / 3.0;
        double p1 = a01 * a01 + a02 * a02 + a12 * a12;
        double d0 = a00 - q, d1 = a11 - q, d2 = a22 - q;
        double p2 = d0 * d0 + d1 * d1 + d2 * d2 + 2.0 * p1;

        double eigmax, eigmin;
        if (p2 <= 0.0) {
            eigmax = q;
            eigmin = q;
        } else {
            double p = sqrt(p2 / 6.0);
            double invp = 1.0 / p;
            double b00 = d0 * invp, b11 = d1 * invp, b22 = d2 * invp;
            double b01 = a01 * invp, b02 = a02 * invp, b12 = a12 * invp;
            double detB = b00 * (b11 * b22 - b12 * b12)
                        - b01 * (b01 * b22 - b12 * b02)
                        + b02 * (b01 * b12 - b11 * b02);
            double r = 0.5 * detB;
            r = fmin(1.0, fmax(-1.0, r));
            double phi = acos(r) / 3.0;
            eigmax = q + 2.0 * p * cos(phi);
            eigmin = q + 2.0 * p * cos(phi + 2.0 * M_PI / 3.0);
        }

        double max_safe = fmax(eigmax, 1e-6);
        double min_safe = fmax(eigmin, 1e-6);
        double ratio = max_safe / min_safe;
        ratio = fmin(fmax(ratio, 1.0), 1e6);
        losses[b] = -log(ratio);
    }
    __syncthreads();

    if (threadIdx.x == 0) {
        double s = 0.0;
        #pragma unroll
        for (int i = 0; i < BATCH; ++i) s += losses[i];
        out[0] = (float)(s / (double)BATCH);
    }
}

extern "C" void kernel_launch(void* const* d_in, const int* in_sizes, int n_in,
                              void* d_out, int out_size, void* d_ws, size_t ws_size,
                              hipStream_t stream) {
    const float* g = (const float*)d_in[0];
    float* out = (float*)d_out;
    double* acc = (double*)d_ws;

    hipMemsetAsync(acc, 0, BATCH * 6 * sizeof(double), stream);

    dim3 grid(128, BATCH, 1);
    accum_kernel<<<grid, 256, 0, stream>>>(g, acc);
    finalize_kernel<<<1, 64, 0, stream>>>(acc, out);
}